// Round 3
// baseline (5561.701 us; speedup 1.0000x reference)
//
#include <hip/hip_runtime.h>
#include <hip/hip_bf16.h>
#include <math.h>

#define SEQ 720
#define NCH 128
#define BATCH 128
#define BN 16384
#define DOM 72
#define PIN 30
#define POUT 30
#define FRQ 33
#define EMB 64
#define PER 24
#define KW 990
#define WST 1712
#define PI_F 3.14159265358979323846f

typedef float2 cf;
__device__ __forceinline__ cf cmac(cf acc, cf a, cf b){
  acc.x += a.x*b.x - a.y*b.y; acc.y += a.x*b.y + a.y*b.x; return acc;
}

// ---------------- P1: small weight compositions ----------------
__global__ void p1_small(const float* WPW, const float* WPb,
                         const float* m1r, const float* m1i, const float* m1br, const float* m1bi,
                         const float* fxr, const float* fxi, const float* fxbr, const float* fxbi,
                         const float* pjr, const float* pji, const float* pjbr, const float* pjbi,
                         cf* C, cf* PM, cf* M2, cf* o3b)
{
  __shared__ cf e64[64];
  __shared__ cf s_d[FRQ];
  __shared__ cf s_rs[PIN];
  __shared__ cf s_o1[FRQ*PIN];
  __shared__ cf s_o2[FRQ*PIN];
  int tid = threadIdx.x;
  if (tid < 64){ float s,c; sincosf(2.f*PI_F*tid/64.f, &s, &c); e64[tid] = make_float2(c, s); }
  __syncthreads();
  // C[f][i] = sum_o e^{-2pi i f o/64} WPW[o][i]   (rfft kernel, negative exponent)
  for (int idx=tid; idx<FRQ*PER; idx+=256){
    int f = idx/PER, i = idx%PER;
    cf acc = make_float2(0.f,0.f);
    for (int o=0;o<EMB;++o){ cf e = e64[(f*o)&63]; float w = WPW[o*PER+i]; acc.x += w*e.x; acc.y -= w*e.y; }
    C[idx] = acc;
  }
  // d[f] = rfft of WP_b
  for (int f=tid; f<FRQ; f+=256){
    cf acc = make_float2(0.f,0.f);
    for (int o=0;o<EMB;++o){ cf e = e64[(f*o)&63]; acc.x += WPb[o]*e.x; acc.y -= WPb[o]*e.y; }
    s_d[f]=acc;
  }
  // PM[q][p] = proj[q,p] + sum_mid proj[q,mid]*mix1[mid,p]   (= PJ·(I+M1))
  for (int idx=tid; idx<POUT*PIN; idx+=256){
    int q = idx/PIN, pp = idx%PIN;
    cf acc = make_float2(pjr[q*PIN+pp], pji[q*PIN+pp]);
    for (int p=0;p<PIN;++p){
      cf a = make_float2(pjr[q*PIN+p], pji[q*PIN+p]);
      cf b = make_float2(m1r[p*PIN+pp], m1i[p*PIN+pp]);
      acc = cmac(acc, a, b);
    }
    PM[idx]=acc;
  }
  // M2 = I + fmix   (row = out index, col = in index)
  for (int idx=tid; idx<FRQ*FRQ; idx+=256){
    int f = idx/FRQ, ff = idx%FRQ;
    cf v = make_float2(fxr[idx], fxi[idx]); if (f==ff) v.x += 1.f;
    M2[idx]=v;
  }
  // rowsums of (I+M1) over in-index
  for (int p=tid; p<PIN; p+=256){
    cf acc = make_float2(1.f,0.f);
    for (int pp=0;pp<PIN;++pp){ acc.x += m1r[p*PIN+pp]; acc.y += m1i[p*PIN+pp]; }
    s_rs[p]=acc;
  }
  __syncthreads();
  // o1 bias part: o1b[f][p'] = d[f]*rs[p'] + bm1[p']
  for (int idx=tid; idx<FRQ*PIN; idx+=256){
    int f = idx/PIN, p = idx%PIN;
    cf v = make_float2(0.f,0.f); v = cmac(v, s_d[f], s_rs[p]);
    v.x += m1br[p]; v.y += m1bi[p];
    s_o1[idx]=v;
  }
  __syncthreads();
  // o2 bias part: o2b[f'][p] = sum_f M2[f',f] o1b[f][p] + bfx[f']
  for (int idx=tid; idx<FRQ*PIN; idx+=256){
    int f = idx/PIN, p = idx%PIN;
    cf acc = make_float2(fxbr[f], fxbi[f]);
    for (int ff=0; ff<FRQ; ++ff){
      cf m2 = make_float2(fxr[f*FRQ+ff], fxi[f*FRQ+ff]); if (f==ff) m2.x += 1.f;
      acc = cmac(acc, m2, s_o1[ff*PIN+p]);
    }
    s_o2[idx]=acc;
  }
  __syncthreads();
  // o3 bias part: o3b[f][q] = sum_p proj[q][p] o2b[f][p] + bp[q]
  for (int idx=tid; idx<FRQ*POUT; idx+=256){
    int f = idx/POUT, q = idx%POUT;
    cf acc = make_float2(pjbr[q], pjbi[q]);
    for (int p=0;p<PIN;++p){
      cf a = make_float2(pjr[q*PIN+p], pji[q*PIN+p]);
      acc = cmac(acc, a, s_o2[f*PIN+p]);
    }
    o3b[f*POUT+q]=acc;
  }
}

// ---------------- P2: Hc[t][q][f] = sc_f * sum_o headW[t,q*64+o] e^{+2pi i f o/64}
__global__ void p2_hc(const float* __restrict__ hW, cf* __restrict__ Hc){
  __shared__ cf e64[64];
  int tid = threadIdx.x;
  if (tid < 64){ float s,c; sincosf(2.f*PI_F*tid/64.f, &s, &c); e64[tid]=make_float2(c,s); }
  __syncthreads();
  int idx = blockIdx.x*256 + tid;
  if (idx >= SEQ*PIN*FRQ) return;
  int f = idx % FRQ; int tq = idx / FRQ; int q = tq % PIN; int t = tq / PIN;
  const float* hw = hW + (size_t)t*1920 + q*64;
  cf acc = make_float2(0.f,0.f);
  for (int o=0;o<EMB;++o){ cf e = e64[(f*o)&63]; float w = hw[o]; acc.x += w*e.x; acc.y += w*e.y; }
  float s = ((f==0)||(f==32)) ? (1.f/64.f) : (2.f/64.f);
  acc.x *= s; acc.y *= s;
  Hc[idx]=acc;
}

// ---------------- P3: V1[t][f][p] = sum_q Hc[t][q][f] PM[q][p]
__global__ void p3_v1(const cf* __restrict__ Hc, const cf* __restrict__ PM, cf* __restrict__ V1){
  __shared__ cf sPM[POUT*PIN];
  int tid=threadIdx.x;
  for (int i=tid;i<POUT*PIN;i+=256) sPM[i]=PM[i];
  __syncthreads();
  int idx = blockIdx.x*256+tid;
  if (idx>=SEQ*FRQ*PIN) return;
  int pp = idx%PIN; int tf = idx/PIN; int f = tf%FRQ; int t = tf/FRQ;
  cf acc = make_float2(0.f,0.f);
  const cf* hc = Hc + (size_t)t*PIN*FRQ + f;
  for (int q=0;q<POUT;++q) acc = cmac(acc, hc[q*FRQ], sPM[q*PIN+pp]);
  V1[idx]=acc;
}

// ---------------- P4: V[t][f][p] = sum_f' V1[t][f'][p] M2[f'][f]
__global__ void p4_v(const cf* __restrict__ V1, const cf* __restrict__ M2, cf* __restrict__ V){
  __shared__ cf sM2[FRQ*FRQ];
  int tid=threadIdx.x;
  for (int i=tid;i<FRQ*FRQ;i+=256) sM2[i]=M2[i];
  __syncthreads();
  int idx = blockIdx.x*256+tid;
  if (idx>=SEQ*FRQ*PIN) return;
  int pp = idx%PIN; int tf = idx/PIN; int ff = tf%FRQ; int t = tf/FRQ;
  cf acc = make_float2(0.f,0.f);
  const cf* v1 = V1 + (size_t)t*FRQ*PIN + pp;
  for (int f=0; f<FRQ; ++f) acc = cmac(acc, v1[f*PIN], sM2[f*FRQ+ff]);
  V[idx]=acc;
}

// ---------------- P5: A1[k][tau] = sum_j Wfreq[k,j] e^{-2pi i j tau/720}
__global__ void p5_a1(const float* __restrict__ fqr, const float* __restrict__ fqi, cf* __restrict__ A1){
  __shared__ cf tbl[720];
  __shared__ cf wrow[DOM];
  int tid=threadIdx.x; int k=blockIdx.x;
  for (int m=tid;m<720;m+=256){ float s,c; sincosf(-2.f*PI_F*(float)m/720.f,&s,&c); tbl[m]=make_float2(c,s); }
  for (int j=tid;j<DOM;j+=256) wrow[j]=make_float2(fqr[k*DOM+j], fqi[k*DOM+j]);
  __syncthreads();
  for (int tau=tid; tau<720; tau+=256){
    cf acc=make_float2(0.f,0.f);
    for (int j=0;j<DOM;++j) acc = cmac(acc, wrow[j], tbl[(j*tau)%720]);
    A1[k*720+tau]=acc;
  }
}

// ---------------- P6: build fused weight row t (f32, stride WST) ----------------
__global__ void p6_bt(const cf* __restrict__ V, const cf* __restrict__ C, const cf* __restrict__ A1,
                      float* __restrict__ BTf){
  __shared__ cf sV[FRQ*PIN];
  __shared__ cf sC[FRQ*PER];
  __shared__ cf sG[DOM];
  int tid=threadIdx.x; int t=blockIdx.x;
  for (int i=tid;i<FRQ*PIN;i+=256) sV[i]=V[(size_t)t*FRQ*PIN+i];
  for (int i=tid;i<FRQ*PER;i+=256) sC[i]=C[i];
  if (tid<DOM){
    int m=(tid*t)%720; float s,c; sincosf(2.f*PI_F*(float)m/720.f,&s,&c);
    float sc=(tid==0)?(1.f/720.f):(2.f/720.f);
    sG[tid]=make_float2(c*sc, s*sc);
  }
  __syncthreads();
  for (int tau=tid; tau<720; tau+=256){
    float mlow=0.f;
    for (int k=0;k<DOM;++k){ cf a=A1[k*720+tau]; cf g=sG[k]; mlow += g.x*a.x - g.y*a.y; }
    int p0 = tau/PER, i0 = tau - p0*PER;
    float mper=0.f;
    for (int f=0; f<FRQ; ++f){ cf v=sV[f*PIN+p0]; cf c=sC[f*PER+i0]; mper += v.x*c.x - v.y*c.y; }
    BTf[(size_t)t*WST + tau] = 0.3f*mlow + 0.7f*mper;
  }
  for (int j=tid;j<KW;j+=256){
    int p=j/FRQ, f=j-p*FRQ;
    BTf[(size_t)t*WST + 720 + j] = 0.7f * sV[f*PIN+p].x;
  }
}

// ---------------- P7: bias[t]
__global__ void p7_bias(const cf* __restrict__ Hc, const cf* __restrict__ o3b,
                        const float* __restrict__ fbr, const float* __restrict__ fbi,
                        const float* __restrict__ headb, float* __restrict__ bias){
  __shared__ cf s_o3[FRQ*POUT];
  __shared__ cf s_bf[DOM];
  int tid=threadIdx.x;
  for (int i=tid;i<FRQ*POUT;i+=256) s_o3[i]=o3b[i];
  for (int i=tid;i<DOM;i+=256) s_bf[i]=make_float2(fbr[i], fbi[i]);
  __syncthreads();
  int t = blockIdx.x*256+tid;
  if (t>=SEQ) return;
  float acc = headb[t];
  const cf* hc = Hc + (size_t)t*PIN*FRQ;
  for (int q=0;q<POUT;++q)
    for (int f=0;f<FRQ;++f){
      cf h = hc[q*FRQ+f]; cf o = s_o3[f*POUT+q];
      acc += h.x*o.x - h.y*o.y;
    }
  float blow=0.f;
  for (int k=0;k<DOM;++k){
    int m=(k*t)%720; float s,c; sincosf(2.f*PI_F*(float)m/720.f,&s,&c);
    float sc=(k==0)?(1.f/720.f):(2.f/720.f);
    blow += sc*(c*s_bf[k].x - s*s_bf[k].y);
  }
  bias[t] = 0.7f*acc + 0.3f*blow;
}

// ---------------- GEMM (f32, simple & obviously correct; f32 OUTPUT) ----------------
// out[b, t, n] = sum_tau BTf[t,tau]*x[b,tau,n] + sum_j BTf[t,720+j]*Wpos[b,n,j] + bias[t]
__global__ __launch_bounds__(256) void gemm_f32(const float* __restrict__ BTf,
                                                const float* __restrict__ x,
                                                const float* __restrict__ Wpos,
                                                const float* __restrict__ bias,
                                                float* __restrict__ out)
{
  __shared__ float sW[8*WST];
  int t0 = blockIdx.x*8;     // 90 t-tiles
  int b  = blockIdx.y;       // 128 batches
  int tid = threadIdx.x;
  for (int i=tid; i<8*(SEQ+KW); i+=256){
    int r = i/(SEQ+KW), c = i - r*(SEQ+KW);
    sW[r*WST+c] = BTf[(size_t)(t0+r)*WST + c];
  }
  __syncthreads();
  int n = tid & 127, h = tid >> 7;
  const float* w0 = sW + (h*4+0)*WST;
  const float* w1 = sW + (h*4+1)*WST;
  const float* w2 = sW + (h*4+2)*WST;
  const float* w3 = sW + (h*4+3)*WST;
  float a0=0.f, a1=0.f, a2=0.f, a3=0.f;
  const float* xb = x + (size_t)b*SEQ*NCH + n;
  #pragma unroll 4
  for (int tau=0; tau<SEQ; ++tau){
    float xv = xb[(size_t)tau*NCH];
    a0 += w0[tau]*xv; a1 += w1[tau]*xv; a2 += w2[tau]*xv; a3 += w3[tau]*xv;
  }
  const float* wp = Wpos + (size_t)(b*NCH+n)*KW;
  #pragma unroll 2
  for (int j=0; j<KW; ++j){
    float wv = wp[j];   // scalar load: wp is only 4B-aligned for odd rows
    a0 += w0[SEQ+j]*wv;
    a1 += w1[SEQ+j]*wv;
    a2 += w2[SEQ+j]*wv;
    a3 += w3[SEQ+j]*wv;
  }
  size_t ob = (size_t)b*SEQ*NCH + n;
  int t = t0 + h*4;
  out[ob + (size_t)(t+0)*NCH] = a0 + bias[t+0];
  out[ob + (size_t)(t+1)*NCH] = a1 + bias[t+1];
  out[ob + (size_t)(t+2)*NCH] = a2 + bias[t+2];
  out[ob + (size_t)(t+3)*NCH] = a3 + bias[t+3];
}

extern "C" void kernel_launch(void* const* d_in, const int* in_sizes, int n_in,
                              void* d_out, int out_size, void* d_ws, size_t ws_size,
                              hipStream_t stream)
{
  const float* x     = (const float*)d_in[0];
  const float* fqWr  = (const float*)d_in[1];
  const float* fqWi  = (const float*)d_in[2];
  const float* fqbr  = (const float*)d_in[3];
  const float* fqbi  = (const float*)d_in[4];
  const float* WPW   = (const float*)d_in[5];
  const float* WPb   = (const float*)d_in[6];
  const float* Wpos  = (const float*)d_in[7];
  const float* m1r   = (const float*)d_in[8];
  const float* m1i   = (const float*)d_in[9];
  const float* m1br  = (const float*)d_in[10];
  const float* m1bi  = (const float*)d_in[11];
  const float* fxr   = (const float*)d_in[12];
  const float* fxi   = (const float*)d_in[13];
  const float* fxbr  = (const float*)d_in[14];
  const float* fxbi  = (const float*)d_in[15];
  const float* pjr   = (const float*)d_in[16];
  const float* pji   = (const float*)d_in[17];
  const float* pjbr  = (const float*)d_in[18];
  const float* pjbi  = (const float*)d_in[19];
  const float* headW = (const float*)d_in[20];
  const float* headb = (const float*)d_in[21];

  char* ws = (char*)d_ws;
  size_t off = 0;
  auto alloc = [&](size_t bytes)->void*{ void* p = ws + off; off += (bytes + 255) & ~(size_t)255; return p; };
  float* BTf = (float*)alloc((size_t)SEQ*WST*4);
  cf* Hc  = (cf*)alloc((size_t)SEQ*PIN*FRQ*8);
  cf* V1  = (cf*)alloc((size_t)SEQ*FRQ*PIN*8);
  cf* V   = (cf*)alloc((size_t)SEQ*FRQ*PIN*8);
  cf* A1  = (cf*)alloc((size_t)DOM*720*8);
  cf* C   = (cf*)alloc((size_t)FRQ*PER*8);
  cf* PM  = (cf*)alloc((size_t)POUT*PIN*8);
  cf* M2  = (cf*)alloc((size_t)FRQ*FRQ*8);
  cf* o3b = (cf*)alloc((size_t)FRQ*POUT*8);
  float* bias = (float*)alloc((size_t)SEQ*4);

  p1_small<<<1,256,0,stream>>>(WPW,WPb, m1r,m1i,m1br,m1bi, fxr,fxi,fxbr,fxbi, pjr,pji,pjbr,pjbi,
                               C,PM,M2,o3b);
  p2_hc<<<(SEQ*PIN*FRQ+255)/256,256,0,stream>>>(headW, Hc);
  p3_v1<<<(SEQ*FRQ*PIN+255)/256,256,0,stream>>>(Hc, PM, V1);
  p4_v<<<(SEQ*FRQ*PIN+255)/256,256,0,stream>>>(V1, M2, V);
  p5_a1<<<DOM,256,0,stream>>>(fqWr, fqWi, A1);
  p6_bt<<<SEQ,256,0,stream>>>(V, C, A1, BTf);
  p7_bias<<<3,256,0,stream>>>(Hc, o3b, fqbr, fqbi, headb, bias);
  gemm_f32<<<dim3(90, BATCH), 256, 0, stream>>>(BTf, x, Wpos, bias, (float*)d_out);
}

// Round 5
// 382.101 us; speedup vs baseline: 14.5556x; 14.5556x over previous
//
#include <hip/hip_runtime.h>
#include <hip/hip_bf16.h>
#include <math.h>

#define SEQ 720
#define NCH 128
#define BATCH 128
#define BN 16384
#define DOM 72
#define PIN 30
#define POUT 30
#define FRQ 33
#define EMB 64
#define PER 24
#define KW 990
#define KP 1728
#define MT 768
#define PI_F 3.14159265358979323846f

typedef float2 cf;
__device__ __forceinline__ cf cmac(cf acc, cf a, cf b){
  acc.x += a.x*b.x - a.y*b.y; acc.y += a.x*b.y + a.y*b.x; return acc;
}

// ---------------- P1: small weight compositions ----------------
__global__ void p1_small(const float* WPW, const float* WPb,
                         const float* m1r, const float* m1i, const float* m1br, const float* m1bi,
                         const float* fxr, const float* fxi, const float* fxbr, const float* fxbi,
                         const float* pjr, const float* pji, const float* pjbr, const float* pjbi,
                         cf* C, cf* PM, cf* M2, cf* o3b)
{
  __shared__ cf e64[64];
  __shared__ cf s_d[FRQ];
  __shared__ cf s_rs[PIN];
  __shared__ cf s_o1[FRQ*PIN];
  __shared__ cf s_o2[FRQ*PIN];
  int tid = threadIdx.x;
  if (tid < 64){ float s,c; sincosf(2.f*PI_F*tid/64.f, &s, &c); e64[tid] = make_float2(c, s); }
  __syncthreads();
  for (int idx=tid; idx<FRQ*PER; idx+=256){
    int f = idx/PER, i = idx%PER;
    cf acc = make_float2(0.f,0.f);
    for (int o=0;o<EMB;++o){ cf e = e64[(f*o)&63]; float w = WPW[o*PER+i]; acc.x += w*e.x; acc.y -= w*e.y; }
    C[idx] = acc;
  }
  for (int f=tid; f<FRQ; f+=256){
    cf acc = make_float2(0.f,0.f);
    for (int o=0;o<EMB;++o){ cf e = e64[(f*o)&63]; acc.x += WPb[o]*e.x; acc.y -= WPb[o]*e.y; }
    s_d[f]=acc;
  }
  for (int idx=tid; idx<POUT*PIN; idx+=256){
    int q = idx/PIN, pp = idx%PIN;
    cf acc = make_float2(pjr[q*PIN+pp], pji[q*PIN+pp]);
    for (int p=0;p<PIN;++p){
      cf a = make_float2(pjr[q*PIN+p], pji[q*PIN+p]);
      cf b = make_float2(m1r[p*PIN+pp], m1i[p*PIN+pp]);
      acc = cmac(acc, a, b);
    }
    PM[idx]=acc;
  }
  for (int idx=tid; idx<FRQ*FRQ; idx+=256){
    int f = idx/FRQ, ff = idx%FRQ;
    cf v = make_float2(fxr[idx], fxi[idx]); if (f==ff) v.x += 1.f;
    M2[idx]=v;
  }
  for (int p=tid; p<PIN; p+=256){
    cf acc = make_float2(1.f,0.f);
    for (int pp=0;pp<PIN;++pp){ acc.x += m1r[p*PIN+pp]; acc.y += m1i[p*PIN+pp]; }
    s_rs[p]=acc;
  }
  __syncthreads();
  for (int idx=tid; idx<FRQ*PIN; idx+=256){
    int f = idx/PIN, p = idx%PIN;
    cf v = make_float2(0.f,0.f); v = cmac(v, s_d[f], s_rs[p]);
    v.x += m1br[p]; v.y += m1bi[p];
    s_o1[idx]=v;
  }
  __syncthreads();
  for (int idx=tid; idx<FRQ*PIN; idx+=256){
    int f = idx/PIN, p = idx%PIN;
    cf acc = make_float2(fxbr[f], fxbi[f]);
    for (int ff=0; ff<FRQ; ++ff){
      cf m2 = make_float2(fxr[f*FRQ+ff], fxi[f*FRQ+ff]); if (f==ff) m2.x += 1.f;
      acc = cmac(acc, m2, s_o1[ff*PIN+p]);
    }
    s_o2[idx]=acc;
  }
  __syncthreads();
  for (int idx=tid; idx<FRQ*POUT; idx+=256){
    int f = idx/POUT, q = idx%POUT;
    cf acc = make_float2(pjbr[q], pjbi[q]);
    for (int p=0;p<PIN;++p){
      cf a = make_float2(pjr[q*PIN+p], pji[q*PIN+p]);
      acc = cmac(acc, a, s_o2[f*PIN+p]);
    }
    o3b[f*POUT+q]=acc;
  }
}

// ---------------- P2: Hc[t][q][f]
__global__ void p2_hc(const float* __restrict__ hW, cf* __restrict__ Hc){
  __shared__ cf e64[64];
  int tid = threadIdx.x;
  if (tid < 64){ float s,c; sincosf(2.f*PI_F*tid/64.f, &s, &c); e64[tid]=make_float2(c,s); }
  __syncthreads();
  int idx = blockIdx.x*256 + tid;
  if (idx >= SEQ*PIN*FRQ) return;
  int f = idx % FRQ; int tq = idx / FRQ; int q = tq % PIN; int t = tq / PIN;
  const float* hw = hW + (size_t)t*1920 + q*64;
  cf acc = make_float2(0.f,0.f);
  for (int o=0;o<EMB;++o){ cf e = e64[(f*o)&63]; float w = hw[o]; acc.x += w*e.x; acc.y += w*e.y; }
  float s = ((f==0)||(f==32)) ? (1.f/64.f) : (2.f/64.f);
  acc.x *= s; acc.y *= s;
  Hc[idx]=acc;
}

// ---------------- P3: V1[t][f][p] = sum_q Hc[t][q][f] PM[q][p]
__global__ void p3_v1(const cf* __restrict__ Hc, const cf* __restrict__ PM, cf* __restrict__ V1){
  __shared__ cf sPM[POUT*PIN];
  int tid=threadIdx.x;
  for (int i=tid;i<POUT*PIN;i+=256) sPM[i]=PM[i];
  __syncthreads();
  int idx = blockIdx.x*256+tid;
  if (idx>=SEQ*FRQ*PIN) return;
  int pp = idx%PIN; int tf = idx/PIN; int f = tf%FRQ; int t = tf/FRQ;
  cf acc = make_float2(0.f,0.f);
  const cf* hc = Hc + (size_t)t*PIN*FRQ + f;
  for (int q=0;q<POUT;++q) acc = cmac(acc, hc[q*FRQ], sPM[q*PIN+pp]);
  V1[idx]=acc;
}

// ---------------- P4: V[t][f][p] = sum_f' V1[t][f'][p] M2[f'][f]
__global__ void p4_v(const cf* __restrict__ V1, const cf* __restrict__ M2, cf* __restrict__ V){
  __shared__ cf sM2[FRQ*FRQ];
  int tid=threadIdx.x;
  for (int i=tid;i<FRQ*FRQ;i+=256) sM2[i]=M2[i];
  __syncthreads();
  int idx = blockIdx.x*256+tid;
  if (idx>=SEQ*FRQ*PIN) return;
  int pp = idx%PIN; int tf = idx/PIN; int ff = tf%FRQ; int t = tf/FRQ;
  cf acc = make_float2(0.f,0.f);
  const cf* v1 = V1 + (size_t)t*FRQ*PIN + pp;
  for (int f=0; f<FRQ; ++f) acc = cmac(acc, v1[f*PIN], sM2[f*FRQ+ff]);
  V[idx]=acc;
}

// ---------------- P5: A1[k][tau]
__global__ void p5_a1(const float* __restrict__ fqr, const float* __restrict__ fqi, cf* __restrict__ A1){
  __shared__ cf tbl[720];
  __shared__ cf wrow[DOM];
  int tid=threadIdx.x; int k=blockIdx.x;
  for (int m=tid;m<720;m+=256){ float s,c; sincosf(-2.f*PI_F*(float)m/720.f,&s,&c); tbl[m]=make_float2(c,s); }
  for (int j=tid;j<DOM;j+=256) wrow[j]=make_float2(fqr[k*DOM+j], fqi[k*DOM+j]);
  __syncthreads();
  for (int tau=tid; tau<720; tau+=256){
    cf acc=make_float2(0.f,0.f);
    for (int j=0;j<DOM;++j) acc = cmac(acc, wrow[j], tbl[(j*tau)%720]);
    A1[k*720+tau]=acc;
  }
}

// ---------------- P6: build fused bf16 weight row t (stride KP, zero-pads cols 1710..1727)
__global__ void p6_bt(const cf* __restrict__ V, const cf* __restrict__ C, const cf* __restrict__ A1,
                      __hip_bfloat16* __restrict__ BTm){
  __shared__ cf sV[FRQ*PIN];
  __shared__ cf sC[FRQ*PER];
  __shared__ cf sG[DOM];
  int tid=threadIdx.x; int t=blockIdx.x;
  for (int i=tid;i<FRQ*PIN;i+=256) sV[i]=V[(size_t)t*FRQ*PIN+i];
  for (int i=tid;i<FRQ*PER;i+=256) sC[i]=C[i];
  if (tid<DOM){
    int m=(tid*t)%720; float s,c; sincosf(2.f*PI_F*(float)m/720.f,&s,&c);
    float sc=(tid==0)?(1.f/720.f):(2.f/720.f);
    sG[tid]=make_float2(c*sc, s*sc);
  }
  __syncthreads();
  for (int tau=tid; tau<720; tau+=256){
    float mlow=0.f;
    for (int k=0;k<DOM;++k){ cf a=A1[k*720+tau]; cf g=sG[k]; mlow += g.x*a.x - g.y*a.y; }
    int p0 = tau/PER, i0 = tau - p0*PER;
    float mper=0.f;
    for (int f=0; f<FRQ; ++f){ cf v=sV[f*PIN+p0]; cf c=sC[f*PER+i0]; mper += v.x*c.x - v.y*c.y; }
    BTm[(size_t)t*KP + tau] = __float2bfloat16(0.3f*mlow + 0.7f*mper);
  }
  for (int j=tid;j<KP-SEQ;j+=256){
    float v = 0.f;
    if (j < KW){ int p=j/FRQ, f=j-p*FRQ; v = 0.7f * sV[f*PIN+p].x; }
    BTm[(size_t)t*KP + SEQ + j] = __float2bfloat16(v);
  }
}

// ---------------- P7: bias[t]
__global__ void p7_bias(const cf* __restrict__ Hc, const cf* __restrict__ o3b,
                        const float* __restrict__ fbr, const float* __restrict__ fbi,
                        const float* __restrict__ headb, float* __restrict__ bias){
  __shared__ cf s_o3[FRQ*POUT];
  __shared__ cf s_bf[DOM];
  int tid=threadIdx.x;
  for (int i=tid;i<FRQ*POUT;i+=256) s_o3[i]=o3b[i];
  for (int i=tid;i<DOM;i+=256) s_bf[i]=make_float2(fbr[i], fbi[i]);
  __syncthreads();
  int t = blockIdx.x*256+tid;
  if (t>=SEQ) return;
  float acc = headb[t];
  const cf* hc = Hc + (size_t)t*PIN*FRQ;
  for (int q=0;q<POUT;++q)
    for (int f=0;f<FRQ;++f){
      cf h = hc[q*FRQ+f]; cf o = s_o3[f*POUT+q];
      acc += h.x*o.x - h.y*o.y;
    }
  float blow=0.f;
  for (int k=0;k<DOM;++k){
    int m=(k*t)%720; float s,c; sincosf(2.f*PI_F*(float)m/720.f,&s,&c);
    float sc=(k==0)?(1.f/720.f):(2.f/720.f);
    blow += sc*(c*s_bf[k].x - s*s_bf[k].y);
  }
  bias[t] = 0.7f*acc + 0.3f*blow;
}

// ---------------- R1: x[b][t][n] -> Abig[b*128+n][t] (bf16, transposed)
__global__ void r1_x(const float* __restrict__ x, __hip_bfloat16* __restrict__ Abig){
  __shared__ float tile[32][33];
  int b = blockIdx.z; int t0=blockIdx.y*32; int n0=blockIdx.x*32;
  int tx=threadIdx.x, ty=threadIdx.y;
  #pragma unroll
  for (int k=0;k<4;++k){
    int t=t0+ty+k*8;
    if (t<SEQ) tile[ty+k*8][tx] = x[((size_t)b*SEQ + t)*NCH + n0+tx];
  }
  __syncthreads();
  #pragma unroll
  for (int k=0;k<4;++k){
    int n = n0+ty+k*8;
    int t = t0+tx;
    if (t<SEQ) Abig[(size_t)(b*NCH+n)*KP + t] = __float2bfloat16(tile[tx][ty+k*8]);
  }
}

// ---------------- R2: Wpos rows -> Abig cols [720,1728) (990 data + 18 zeros)
__global__ void r2_wpos(const float* __restrict__ Wp, __hip_bfloat16* __restrict__ Abig){
  int bn = blockIdx.x; int tid=threadIdx.x;
  const float* src = Wp + (size_t)bn*KW;
  __hip_bfloat16* dst = Abig + (size_t)bn*KP + SEQ;
  for (int j=tid; j<KP-SEQ; j+=256){
    float v = (j<KW)? src[j] : 0.f;
    dst[j] = __float2bfloat16(v);
  }
}

// ---------------- GEMM: out[b,t,n] = sum_k BT[t,k]*Abig[bn,k] + bias[t] (f32 out)
typedef __attribute__((ext_vector_type(8))) short bfrag_t;
typedef __attribute__((ext_vector_type(4))) float accf_t;
typedef __attribute__((address_space(1))) void gvoid;
typedef __attribute__((address_space(3))) void lvoid;

__device__ __forceinline__ void gload16(const void* g, void* l){
  __builtin_amdgcn_global_load_lds((gvoid*)(g), (lvoid*)(l), 16, 0, 0);
}

__global__ __launch_bounds__(256) void gemm_main(const __hip_bfloat16* __restrict__ BTm,
                                                 const __hip_bfloat16* __restrict__ Abig,
                                                 const float* __restrict__ bias,
                                                 float* __restrict__ out)
{
  __shared__ __hip_bfloat16 At[128*32];
  __shared__ __hip_bfloat16 Bt[128*32];
  int tid = threadIdx.x;
  int lane = tid & 63;
  int wv = tid >> 6;
  int wr = wv >> 1, wc = wv & 1;
  int t0 = blockIdx.y*128, bn0 = blockIdx.x*128;

  accf_t acc[4][4];
  #pragma unroll
  for (int i=0;i<4;++i)
    #pragma unroll
    for (int j=0;j<4;++j) acc[i][j] = (accf_t){0.f,0.f,0.f,0.f};

  // staging: lin = L*256+tid ; row=lin>>2 ; unit u=lin&3 ; source k-unit XOR-swizzled
  int lin0 = tid, lin1 = 256+tid;
  int row0 = lin0>>2, ug0 = (lin0&3) ^ ((row0>>1)&3);
  int row1 = lin1>>2, ug1 = (lin1&3) ^ ((row1>>1)&3);
  const __hip_bfloat16* gA0 = BTm  + (size_t)(t0 +row0)*KP + ug0*8;
  const __hip_bfloat16* gA1 = BTm  + (size_t)(t0 +row1)*KP + ug1*8;
  const __hip_bfloat16* gB0 = Abig + (size_t)(bn0+row0)*KP + ug0*8;
  const __hip_bfloat16* gB1 = Abig + (size_t)(bn0+row1)*KP + ug1*8;
  char* lA0 = (char*)At + lin0*16; char* lA1 = (char*)At + lin1*16;
  char* lB0 = (char*)Bt + lin0*16; char* lB1 = (char*)Bt + lin1*16;

  int g = lane>>4;
  int arow = wr*64 + (lane&15);
  int brow = wc*64 + (lane&15);

  for (int ks=0; ks<KP/32; ++ks){
    int k0 = ks*32;
    gload16(gA0 + k0, lA0);
    gload16(gA1 + k0, lA1);
    gload16(gB0 + k0, lB0);
    gload16(gB1 + k0, lB1);
    __syncthreads();   // drains vmcnt before ds_read
    bfrag_t af[4], bb[4];
    #pragma unroll
    for (int mi=0;mi<4;++mi){
      int r = arow + mi*16;
      int uu = g ^ ((r>>1)&3);
      af[mi] = *(const bfrag_t*)((const char*)At + r*64 + uu*16);
    }
    #pragma unroll
    for (int ni=0;ni<4;++ni){
      int r = brow + ni*16;
      int uu = g ^ ((r>>1)&3);
      bb[ni] = *(const bfrag_t*)((const char*)Bt + r*64 + uu*16);
    }
    #pragma unroll
    for (int mi=0;mi<4;++mi)
      #pragma unroll
      for (int ni=0;ni<4;++ni)
        acc[mi][ni] = __builtin_amdgcn_mfma_f32_16x16x32_bf16(af[mi], bb[ni], acc[mi][ni], 0, 0, 0);
    __syncthreads();   // compute done before next stage overwrites
  }

  #pragma unroll
  for (int mi=0;mi<4;++mi){
    int tbase = t0 + wr*64 + mi*16 + (lane>>4)*4;
    #pragma unroll
    for (int ni=0;ni<4;++ni){
      int col = bn0 + wc*64 + ni*16 + (lane&15);
      int b = col>>7, n = col&127;
      size_t obase = (size_t)b*(SEQ*NCH) + n;
      #pragma unroll
      for (int r=0;r<4;++r){
        int t = tbase + r;
        if (t<SEQ) out[obase + (size_t)t*NCH] = acc[mi][ni][r] + bias[t];
      }
    }
  }
}

extern "C" void kernel_launch(void* const* d_in, const int* in_sizes, int n_in,
                              void* d_out, int out_size, void* d_ws, size_t ws_size,
                              hipStream_t stream)
{
  const float* x     = (const float*)d_in[0];
  const float* fqWr  = (const float*)d_in[1];
  const float* fqWi  = (const float*)d_in[2];
  const float* fqbr  = (const float*)d_in[3];
  const float* fqbi  = (const float*)d_in[4];
  const float* WPW   = (const float*)d_in[5];
  const float* WPb   = (const float*)d_in[6];
  const float* Wpos  = (const float*)d_in[7];
  const float* m1r   = (const float*)d_in[8];
  const float* m1i   = (const float*)d_in[9];
  const float* m1br  = (const float*)d_in[10];
  const float* m1bi  = (const float*)d_in[11];
  const float* fxr   = (const float*)d_in[12];
  const float* fxi   = (const float*)d_in[13];
  const float* fxbr  = (const float*)d_in[14];
  const float* fxbi  = (const float*)d_in[15];
  const float* pjr   = (const float*)d_in[16];
  const float* pji   = (const float*)d_in[17];
  const float* pjbr  = (const float*)d_in[18];
  const float* pjbi  = (const float*)d_in[19];
  const float* headW = (const float*)d_in[20];
  const float* headb = (const float*)d_in[21];

  char* ws = (char*)d_ws;
  size_t off = 0;
  auto alloc = [&](size_t bytes)->void*{ void* p = ws + off; off += (bytes + 255) & ~(size_t)255; return p; };
  __hip_bfloat16* Abig = (__hip_bfloat16*)alloc((size_t)BN*KP*2);
  __hip_bfloat16* BTm  = (__hip_bfloat16*)alloc((size_t)MT*KP*2);
  cf* Hc  = (cf*)alloc((size_t)SEQ*PIN*FRQ*8);
  cf* V1  = (cf*)alloc((size_t)SEQ*FRQ*PIN*8);
  cf* V   = (cf*)alloc((size_t)SEQ*FRQ*PIN*8);
  cf* A1  = (cf*)alloc((size_t)DOM*720*8);
  cf* C   = (cf*)alloc((size_t)FRQ*PER*8);
  cf* PM  = (cf*)alloc((size_t)POUT*PIN*8);
  cf* M2  = (cf*)alloc((size_t)FRQ*FRQ*8);
  cf* o3b = (cf*)alloc((size_t)FRQ*POUT*8);
  float* bias = (float*)alloc((size_t)SEQ*4);

  p1_small<<<1,256,0,stream>>>(WPW,WPb, m1r,m1i,m1br,m1bi, fxr,fxi,fxbr,fxbi, pjr,pji,pjbr,pjbi,
                               C,PM,M2,o3b);
  p2_hc<<<(SEQ*PIN*FRQ+255)/256,256,0,stream>>>(headW, Hc);
  p3_v1<<<(SEQ*FRQ*PIN+255)/256,256,0,stream>>>(Hc, PM, V1);
  p4_v<<<(SEQ*FRQ*PIN+255)/256,256,0,stream>>>(V1, M2, V);
  p5_a1<<<DOM,256,0,stream>>>(fqWr, fqWi, A1);
  p6_bt<<<SEQ,256,0,stream>>>(V, C, A1, BTm);
  p7_bias<<<3,256,0,stream>>>(Hc, o3b, fqbr, fqbi, headb, bias);
  r1_x<<<dim3(4,23,BATCH), dim3(32,8), 0, stream>>>(x, Abig);
  r2_wpos<<<BN,256,0,stream>>>(Wpos, Abig);
  gemm_main<<<dim3(BN/128, MT/128), 256, 0, stream>>>(BTm, Abig, bias, (float*)d_out);
}

// Round 6
// 202.530 us; speedup vs baseline: 27.4612x; 1.8866x over previous
//
#include <hip/hip_runtime.h>
#include <hip/hip_bf16.h>
#include <math.h>

#define SEQ 720
#define NCH 128
#define BATCH 128
#define BN 16384
#define DOM 72
#define PIN 30
#define POUT 30
#define FRQ 33
#define EMB 64
#define PER 24
#define KW 990
#define KP 1728
#define MT 768
#define PI_F 3.14159265358979323846f

typedef float2 cf;
__device__ __forceinline__ cf cmac(cf acc, cf a, cf b){
  acc.x += a.x*b.x - a.y*b.y; acc.y += a.x*b.y + a.y*b.x; return acc;
}
__device__ __forceinline__ short b2s(float f){
  __hip_bfloat16 h = __float2bfloat16(f);
  return *reinterpret_cast<short*>(&h);
}

// ---------------- P1: small weight compositions ----------------
__global__ void p1_small(const float* WPW, const float* WPb,
                         const float* m1r, const float* m1i, const float* m1br, const float* m1bi,
                         const float* fxr, const float* fxi, const float* fxbr, const float* fxbi,
                         const float* pjr, const float* pji, const float* pjbr, const float* pjbi,
                         cf* C, cf* PM, cf* M2, cf* o3b)
{
  __shared__ cf e64[64];
  __shared__ cf s_d[FRQ];
  __shared__ cf s_rs[PIN];
  __shared__ cf s_o1[FRQ*PIN];
  __shared__ cf s_o2[FRQ*PIN];
  int tid = threadIdx.x;
  if (tid < 64){ float s,c; sincosf(2.f*PI_F*tid/64.f, &s, &c); e64[tid] = make_float2(c, s); }
  __syncthreads();
  for (int idx=tid; idx<FRQ*PER; idx+=256){
    int f = idx/PER, i = idx%PER;
    cf acc = make_float2(0.f,0.f);
    for (int o=0;o<EMB;++o){ cf e = e64[(f*o)&63]; float w = WPW[o*PER+i]; acc.x += w*e.x; acc.y -= w*e.y; }
    C[idx] = acc;
  }
  for (int f=tid; f<FRQ; f+=256){
    cf acc = make_float2(0.f,0.f);
    for (int o=0;o<EMB;++o){ cf e = e64[(f*o)&63]; acc.x += WPb[o]*e.x; acc.y -= WPb[o]*e.y; }
    s_d[f]=acc;
  }
  for (int idx=tid; idx<POUT*PIN; idx+=256){
    int q = idx/PIN, pp = idx%PIN;
    cf acc = make_float2(pjr[q*PIN+pp], pji[q*PIN+pp]);
    for (int p=0;p<PIN;++p){
      cf a = make_float2(pjr[q*PIN+p], pji[q*PIN+p]);
      cf b = make_float2(m1r[p*PIN+pp], m1i[p*PIN+pp]);
      acc = cmac(acc, a, b);
    }
    PM[idx]=acc;
  }
  for (int idx=tid; idx<FRQ*FRQ; idx+=256){
    int f = idx/FRQ, ff = idx%FRQ;
    cf v = make_float2(fxr[idx], fxi[idx]); if (f==ff) v.x += 1.f;
    M2[idx]=v;
  }
  for (int p=tid; p<PIN; p+=256){
    cf acc = make_float2(1.f,0.f);
    for (int pp=0;pp<PIN;++pp){ acc.x += m1r[p*PIN+pp]; acc.y += m1i[p*PIN+pp]; }
    s_rs[p]=acc;
  }
  __syncthreads();
  for (int idx=tid; idx<FRQ*PIN; idx+=256){
    int f = idx/PIN, p = idx%PIN;
    cf v = make_float2(0.f,0.f); v = cmac(v, s_d[f], s_rs[p]);
    v.x += m1br[p]; v.y += m1bi[p];
    s_o1[idx]=v;
  }
  __syncthreads();
  for (int idx=tid; idx<FRQ*PIN; idx+=256){
    int f = idx/PIN, p = idx%PIN;
    cf acc = make_float2(fxbr[f], fxbi[f]);
    for (int ff=0; ff<FRQ; ++ff){
      cf m2 = make_float2(fxr[f*FRQ+ff], fxi[f*FRQ+ff]); if (f==ff) m2.x += 1.f;
      acc = cmac(acc, m2, s_o1[ff*PIN+p]);
    }
    s_o2[idx]=acc;
  }
  __syncthreads();
  for (int idx=tid; idx<FRQ*POUT; idx+=256){
    int f = idx/POUT, q = idx%POUT;
    cf acc = make_float2(pjbr[q], pjbi[q]);
    for (int p=0;p<PIN;++p){
      cf a = make_float2(pjr[q*PIN+p], pji[q*PIN+p]);
      acc = cmac(acc, a, s_o2[f*PIN+p]);
    }
    o3b[f*POUT+q]=acc;
  }
}

// ---------------- P5: A1 split real/imag planes ----------------
__global__ void p5_a1(const float* __restrict__ fqr, const float* __restrict__ fqi,
                      float* __restrict__ A1r, float* __restrict__ A1i){
  __shared__ cf tbl[720];
  __shared__ cf wrow[DOM];
  int tid=threadIdx.x; int k=blockIdx.x;
  for (int m=tid;m<720;m+=256){ float s,c; sincosf(-2.f*PI_F*(float)m/720.f,&s,&c); tbl[m]=make_float2(c,s); }
  for (int j=tid;j<DOM;j+=256) wrow[j]=make_float2(fqr[k*DOM+j], fqi[k*DOM+j]);
  __syncthreads();
  for (int tau=tid; tau<720; tau+=256){
    cf acc=make_float2(0.f,0.f);
    for (int j=0;j<DOM;++j) acc = cmac(acc, wrow[j], tbl[(j*tau)%720]);
    A1r[k*720+tau]=acc.x;
    A1i[k*720+tau]=acc.y;
  }
}

// ---------------- P5M: Mlow[t][tau] = sum_k Gr[t,k]A1r[k,tau] - Gi[t,k]A1i[k,tau]
__global__ __launch_bounds__(256) void p5m_mlow(const float* __restrict__ A1r,
                                                const float* __restrict__ A1i,
                                                float* __restrict__ Mlow){
  __shared__ float sG[16*144];   // [tt][0..71]=Gr, [tt][72..143]=Gi
  __shared__ float sA[144*16];   // [k][tc]=A1r, [72+k][tc]=A1i
  int t0 = blockIdx.y*16, tau0 = blockIdx.x*16;
  int tid = threadIdx.x;
  for (int i=tid; i<16*72; i+=256){
    int tt=i/72, k=i%72;
    int m = ((t0+tt)*k) % 720;
    float s,c; sincosf(2.f*PI_F*(float)m/720.f,&s,&c);
    float sc = (k==0)?(1.f/720.f):(2.f/720.f);
    sG[tt*144+k]    = c*sc;
    sG[tt*144+72+k] = s*sc;
  }
  for (int i=tid; i<72*16; i+=256){
    int k=i/16, tc=i%16;
    sA[k*16+tc]      = A1r[k*720+tau0+tc];
    sA[(72+k)*16+tc] = A1i[k*720+tau0+tc];
  }
  __syncthreads();
  int tt=tid/16, tc=tid%16;
  float acc=0.f;
  #pragma unroll 8
  for (int k=0;k<72;++k)
    acc += sG[tt*144+k]*sA[k*16+tc] - sG[tt*144+72+k]*sA[(72+k)*16+tc];
  Mlow[(size_t)(t0+tt)*720 + tau0+tc] = acc;
}

// ---------------- P_BIG: per-t merged p2+p3+p4+p7 -> V[t], bias[t] ----------------
__global__ __launch_bounds__(256) void p_big(const float* __restrict__ hW,
                    const cf* __restrict__ PM, const cf* __restrict__ M2, const cf* __restrict__ o3b,
                    const float* __restrict__ fbr, const float* __restrict__ fbi,
                    const float* __restrict__ headb,
                    cf* __restrict__ V, float* __restrict__ bias){
  __shared__ cf e64[64];
  __shared__ float shw[1920];
  __shared__ cf sHc[990];
  __shared__ cf sV1[990];
  __shared__ cf sPM[POUT*PIN];
  __shared__ cf sM2[FRQ*FRQ];
  __shared__ cf sO3[FRQ*POUT];
  __shared__ float red[256];
  int tid=threadIdx.x; int t=blockIdx.x;
  if (tid<64){ float s,c; sincosf(2.f*PI_F*tid/64.f,&s,&c); e64[tid]=make_float2(c,s); }
  for (int i=tid;i<1920;i+=256) shw[i]=hW[(size_t)t*1920+i];
  for (int i=tid;i<POUT*PIN;i+=256) sPM[i]=PM[i];
  for (int i=tid;i<FRQ*FRQ;i+=256) sM2[i]=M2[i];
  for (int i=tid;i<FRQ*POUT;i+=256) sO3[i]=o3b[i];
  __syncthreads();
  // Hc[q][f]
  for (int idx=tid; idx<990; idx+=256){
    int q=idx/FRQ, f=idx%FRQ;
    cf acc=make_float2(0.f,0.f);
    const float* hw = &shw[q*64];
    for (int o=0;o<EMB;++o){ cf e=e64[(f*o)&63]; float w=hw[o]; acc.x+=w*e.x; acc.y+=w*e.y; }
    float s=((f==0)||(f==32))?(1.f/64.f):(2.f/64.f);
    sHc[idx]=make_float2(acc.x*s, acc.y*s);
  }
  __syncthreads();
  // V1[f][p] = sum_q Hc[q][f] PM[q][p]
  for (int idx=tid; idx<990; idx+=256){
    int f=idx/PIN, p=idx%PIN;
    cf acc=make_float2(0.f,0.f);
    for (int q=0;q<POUT;++q) acc=cmac(acc, sHc[q*FRQ+f], sPM[q*PIN+p]);
    sV1[idx]=acc;
  }
  __syncthreads();
  // V[ff][pp] = sum_f V1[f][pp] M2[f][ff]
  for (int idx=tid; idx<990; idx+=256){
    int ff=idx/PIN, pp=idx%PIN;
    cf acc=make_float2(0.f,0.f);
    for (int f=0;f<FRQ;++f) acc=cmac(acc, sV1[f*PIN+pp], sM2[f*FRQ+ff]);
    V[(size_t)t*990+idx]=acc;
  }
  // bias[t] = 0.7*(headb[t] + sum_{q,f} Re(Hc[q][f] * o3b[f][q])) + 0.3*blow
  float part=0.f;
  for (int idx=tid; idx<990; idx+=256){
    int q=idx/FRQ, f=idx%FRQ;
    cf h=sHc[idx]; cf o=sO3[f*POUT+q];
    part += h.x*o.x - h.y*o.y;
  }
  part *= 0.7f;
  if (tid<DOM){
    int m=(tid*t)%720; float s,c; sincosf(2.f*PI_F*(float)m/720.f,&s,&c);
    float sc=(tid==0)?(1.f/720.f):(2.f/720.f);
    part += 0.3f*sc*(c*fbr[tid] - s*fbi[tid]);
  }
  red[tid]=part; __syncthreads();
  for (int s=128;s>0;s>>=1){ if (tid<s) red[tid]+=red[tid+s]; __syncthreads(); }
  if (tid==0) bias[t] = red[0] + 0.7f*headb[t];
}

// ---------------- P6: build fused bf16 weight row t ----------------
__global__ void p6_bt(const cf* __restrict__ V, const cf* __restrict__ C,
                      const float* __restrict__ Mlow, __hip_bfloat16* __restrict__ BTm){
  __shared__ cf sV[990];
  __shared__ cf sC[FRQ*PER];
  int tid=threadIdx.x; int t=blockIdx.x;
  for (int i=tid;i<990;i+=256) sV[i]=V[(size_t)t*990+i];
  for (int i=tid;i<FRQ*PER;i+=256) sC[i]=C[i];
  __syncthreads();
  const float* ml = Mlow + (size_t)t*720;
  for (int tau=tid; tau<720; tau+=256){
    int p0 = tau/PER, i0 = tau - p0*PER;
    float mper=0.f;
    for (int f=0; f<FRQ; ++f){ cf v=sV[f*PIN+p0]; cf c=sC[f*PER+i0]; mper += v.x*c.x - v.y*c.y; }
    BTm[(size_t)t*KP + tau] = __float2bfloat16(0.3f*ml[tau] + 0.7f*mper);
  }
  for (int j=tid;j<KP-SEQ;j+=256){
    float v = 0.f;
    if (j < KW){ int p=j/FRQ, f=j-p*FRQ; v = 0.7f * sV[f*PIN+p].x; }
    BTm[(size_t)t*KP + SEQ + j] = __float2bfloat16(v);
  }
}

// ---------------- R1: x[b][t][n] -> Abig[b*128+n][t] (bf16, 64x64 tiles, short4 stores)
__global__ __launch_bounds__(256) void r1_x(const float* __restrict__ x, __hip_bfloat16* __restrict__ Abig){
  __shared__ float tile[64][65];
  int b = blockIdx.z; int t0=blockIdx.y*64; int n0=blockIdx.x*64;
  int tid=threadIdx.x;
  int c = tid & 63, r0 = tid >> 6;   // r0 in 0..3
  #pragma unroll
  for (int s=0;s<16;++s){
    int r = r0 + s*4;
    int t = t0 + r;
    tile[r][c] = (t<SEQ) ? x[((size_t)b*SEQ + t)*NCH + n0 + c] : 0.f;
  }
  __syncthreads();
  int nn0 = tid >> 4;      // 0..15
  int tq  = tid & 15;      // t-quad
  int tt  = t0 + tq*4;
  #pragma unroll
  for (int s=0;s<4;++s){
    int nn = nn0 + s*16;
    short4 v;
    v.x = b2s(tile[tq*4+0][nn]);
    v.y = b2s(tile[tq*4+1][nn]);
    v.z = b2s(tile[tq*4+2][nn]);
    v.w = b2s(tile[tq*4+3][nn]);
    __hip_bfloat16* dst = Abig + (size_t)(b*NCH + n0+nn)*KP + tt;
    if (tt+3 < SEQ){
      *reinterpret_cast<short4*>(dst) = v;
    } else {
      short sv[4] = {v.x, v.y, v.z, v.w};
      for (int j=0;j<4;++j) if (tt+j < SEQ) *reinterpret_cast<short*>(dst+j) = sv[j];
    }
  }
}

// ---------------- R2: Wpos rows -> Abig cols [720,1728), vectorized
__global__ __launch_bounds__(256) void r2_wpos(const float* __restrict__ Wp, __hip_bfloat16* __restrict__ Abig){
  int bn = blockIdx.x; int tid=threadIdx.x;
  int j = tid*4;
  if (j >= KP-SEQ) return;
  const float* src = Wp + (size_t)bn*KW;
  float f0,f1,f2,f3;
  if (j+3 < KW){
    float2 u = *reinterpret_cast<const float2*>(src+j);
    float2 w = *reinterpret_cast<const float2*>(src+j+2);
    f0=u.x; f1=u.y; f2=w.x; f3=w.y;
  } else {
    f0=(j  <KW)?src[j  ]:0.f; f1=(j+1<KW)?src[j+1]:0.f;
    f2=(j+2<KW)?src[j+2]:0.f; f3=(j+3<KW)?src[j+3]:0.f;
  }
  short4 v = { b2s(f0), b2s(f1), b2s(f2), b2s(f3) };
  *reinterpret_cast<short4*>(Abig + (size_t)bn*KP + SEQ + j) = v;
}

// ---------------- GEMM: out[b,t,n] = sum_k BT[t,k]*Abig[bn,k] + bias[t] (f32 out)
typedef __attribute__((ext_vector_type(8))) short bfrag_t;
typedef __attribute__((ext_vector_type(4))) float accf_t;
typedef __attribute__((address_space(1))) void gvoid;
typedef __attribute__((address_space(3))) void lvoid;

__device__ __forceinline__ void gload16(const void* g, void* l){
  __builtin_amdgcn_global_load_lds((gvoid*)(g), (lvoid*)(l), 16, 0, 0);
}

__global__ __launch_bounds__(256) void gemm_main(const __hip_bfloat16* __restrict__ BTm,
                                                 const __hip_bfloat16* __restrict__ Abig,
                                                 const float* __restrict__ bias,
                                                 float* __restrict__ out)
{
  __shared__ __hip_bfloat16 At[128*32];
  __shared__ __hip_bfloat16 Bt[128*32];
  int tid = threadIdx.x;
  int lane = tid & 63;
  int wv = tid >> 6;
  int wr = wv >> 1, wc = wv & 1;
  int t0 = blockIdx.y*128, bn0 = blockIdx.x*128;

  accf_t acc[4][4];
  #pragma unroll
  for (int i=0;i<4;++i)
    #pragma unroll
    for (int j=0;j<4;++j) acc[i][j] = (accf_t){0.f,0.f,0.f,0.f};

  int lin0 = tid, lin1 = 256+tid;
  int row0 = lin0>>2, ug0 = (lin0&3) ^ ((row0>>1)&3);
  int row1 = lin1>>2, ug1 = (lin1&3) ^ ((row1>>1)&3);
  const __hip_bfloat16* gA0 = BTm  + (size_t)(t0 +row0)*KP + ug0*8;
  const __hip_bfloat16* gA1 = BTm  + (size_t)(t0 +row1)*KP + ug1*8;
  const __hip_bfloat16* gB0 = Abig + (size_t)(bn0+row0)*KP + ug0*8;
  const __hip_bfloat16* gB1 = Abig + (size_t)(bn0+row1)*KP + ug1*8;
  char* lA0 = (char*)At + lin0*16; char* lA1 = (char*)At + lin1*16;
  char* lB0 = (char*)Bt + lin0*16; char* lB1 = (char*)Bt + lin1*16;

  int g = lane>>4;
  int arow = wr*64 + (lane&15);
  int brow = wc*64 + (lane&15);

  for (int ks=0; ks<KP/32; ++ks){
    int k0 = ks*32;
    gload16(gA0 + k0, lA0);
    gload16(gA1 + k0, lA1);
    gload16(gB0 + k0, lB0);
    gload16(gB1 + k0, lB1);
    __syncthreads();
    bfrag_t af[4], bb[4];
    #pragma unroll
    for (int mi=0;mi<4;++mi){
      int r = arow + mi*16;
      int uu = g ^ ((r>>1)&3);
      af[mi] = *(const bfrag_t*)((const char*)At + r*64 + uu*16);
    }
    #pragma unroll
    for (int ni=0;ni<4;++ni){
      int r = brow + ni*16;
      int uu = g ^ ((r>>1)&3);
      bb[ni] = *(const bfrag_t*)((const char*)Bt + r*64 + uu*16);
    }
    #pragma unroll
    for (int mi=0;mi<4;++mi)
      #pragma unroll
      for (int ni=0;ni<4;++ni)
        acc[mi][ni] = __builtin_amdgcn_mfma_f32_16x16x32_bf16(af[mi], bb[ni], acc[mi][ni], 0, 0, 0);
    __syncthreads();
  }

  #pragma unroll
  for (int mi=0;mi<4;++mi){
    int tbase = t0 + wr*64 + mi*16 + (lane>>4)*4;
    #pragma unroll
    for (int ni=0;ni<4;++ni){
      int col = bn0 + wc*64 + ni*16 + (lane&15);
      int b = col>>7, n = col&127;
      size_t obase = (size_t)b*(SEQ*NCH) + n;
      #pragma unroll
      for (int r=0;r<4;++r){
        int t = tbase + r;
        if (t<SEQ) out[obase + (size_t)t*NCH] = acc[mi][ni][r] + bias[t];
      }
    }
  }
}

extern "C" void kernel_launch(void* const* d_in, const int* in_sizes, int n_in,
                              void* d_out, int out_size, void* d_ws, size_t ws_size,
                              hipStream_t stream)
{
  const float* x     = (const float*)d_in[0];
  const float* fqWr  = (const float*)d_in[1];
  const float* fqWi  = (const float*)d_in[2];
  const float* fqbr  = (const float*)d_in[3];
  const float* fqbi  = (const float*)d_in[4];
  const float* WPW   = (const float*)d_in[5];
  const float* WPb   = (const float*)d_in[6];
  const float* Wpos  = (const float*)d_in[7];
  const float* m1r   = (const float*)d_in[8];
  const float* m1i   = (const float*)d_in[9];
  const float* m1br  = (const float*)d_in[10];
  const float* m1bi  = (const float*)d_in[11];
  const float* fxr   = (const float*)d_in[12];
  const float* fxi   = (const float*)d_in[13];
  const float* fxbr  = (const float*)d_in[14];
  const float* fxbi  = (const float*)d_in[15];
  const float* pjr   = (const float*)d_in[16];
  const float* pji   = (const float*)d_in[17];
  const float* pjbr  = (const float*)d_in[18];
  const float* pjbi  = (const float*)d_in[19];
  const float* headW = (const float*)d_in[20];
  const float* headb = (const float*)d_in[21];

  char* ws = (char*)d_ws;
  size_t off = 0;
  auto alloc = [&](size_t bytes)->void*{ void* p = ws + off; off += (bytes + 255) & ~(size_t)255; return p; };
  __hip_bfloat16* Abig = (__hip_bfloat16*)alloc((size_t)BN*KP*2);
  __hip_bfloat16* BTm  = (__hip_bfloat16*)alloc((size_t)MT*KP*2);
  cf* V    = (cf*)alloc((size_t)SEQ*990*8);
  float* A1r = (float*)alloc((size_t)DOM*720*4);
  float* A1i = (float*)alloc((size_t)DOM*720*4);
  float* Mlow= (float*)alloc((size_t)SEQ*720*4);
  cf* C   = (cf*)alloc((size_t)FRQ*PER*8);
  cf* PM  = (cf*)alloc((size_t)POUT*PIN*8);
  cf* M2  = (cf*)alloc((size_t)FRQ*FRQ*8);
  cf* o3b = (cf*)alloc((size_t)FRQ*POUT*8);
  float* bias = (float*)alloc((size_t)SEQ*4);

  p1_small<<<1,256,0,stream>>>(WPW,WPb, m1r,m1i,m1br,m1bi, fxr,fxi,fxbr,fxbi, pjr,pji,pjbr,pjbi,
                               C,PM,M2,o3b);
  p5_a1<<<DOM,256,0,stream>>>(fqWr, fqWi, A1r, A1i);
  p5m_mlow<<<dim3(45,45),256,0,stream>>>(A1r, A1i, Mlow);
  p_big<<<SEQ,256,0,stream>>>(headW, PM, M2, o3b, fqbr, fqbi, headb, V, bias);
  p6_bt<<<SEQ,256,0,stream>>>(V, C, Mlow, BTm);
  r1_x<<<dim3(2,12,BATCH), 256, 0, stream>>>(x, Abig);
  r2_wpos<<<BN,256,0,stream>>>(Wpos, Abig);
  gemm_main<<<dim3(BN/128, MT/128), 256, 0, stream>>>(BTm, Abig, bias, (float*)d_out);
}

// Round 8
// 182.923 us; speedup vs baseline: 30.4047x; 1.1072x over previous
//
#include <hip/hip_runtime.h>
#include <hip/hip_bf16.h>
#include <math.h>

#define SEQ 720
#define NCH 128
#define BATCH 128
#define BN 16384
#define DOM 72
#define PIN 30
#define POUT 30
#define FRQ 33
#define EMB 64
#define PER 24
#define KW 990
#define KP 1728
#define MT 768
#define PI_F 3.14159265358979323846f

typedef float2 cf;
__device__ __forceinline__ cf cmac(cf acc, cf a, cf b){
  acc.x += a.x*b.x - a.y*b.y; acc.y += a.x*b.y + a.y*b.x; return acc;
}
__device__ __forceinline__ short b2s(float f){
  __hip_bfloat16 h = __float2bfloat16(f);
  return *reinterpret_cast<short*>(&h);
}

// ---------------- P1: small weight compositions (LDS-staged) ----------------
__global__ __launch_bounds__(256) void p1_small(const float* __restrict__ WPW, const float* __restrict__ WPb,
                         const float* __restrict__ m1r, const float* __restrict__ m1i,
                         const float* __restrict__ m1br, const float* __restrict__ m1bi,
                         const float* __restrict__ fxr, const float* __restrict__ fxi,
                         const float* __restrict__ fxbr, const float* __restrict__ fxbi,
                         const float* __restrict__ pjr, const float* __restrict__ pji,
                         const float* __restrict__ pjbr, const float* __restrict__ pjbi,
                         cf* C, cf* PM, cf* M2, cf* o3b)
{
  __shared__ cf e64[64];
  __shared__ float sW[EMB*PER];      // 1536
  __shared__ float sWb[EMB];
  __shared__ float sM1r[PIN*PIN], sM1i[PIN*PIN];      // 900 each
  __shared__ float sFxr[FRQ*FRQ], sFxi[FRQ*FRQ];      // 1089 each
  __shared__ float sPjr[POUT*PIN], sPji[POUT*PIN];    // 900 each
  __shared__ float sB[6*33];         // m1br,m1bi,fxbr,fxbi,pjbr,pjbi (padded 33)
  __shared__ cf s_d[FRQ];
  __shared__ cf s_rs[PIN];
  __shared__ cf s_o1[FRQ*PIN];
  __shared__ cf s_o2[FRQ*PIN];
  int tid = threadIdx.x;
  // ---- coalesced staging ----
  if (tid < 64){ float s,c; sincosf(2.f*PI_F*tid/64.f, &s, &c); e64[tid] = make_float2(c, s); }
  for (int i=tid; i<EMB*PER; i+=256) sW[i]=WPW[i];
  if (tid < EMB) sWb[tid]=WPb[tid];
  for (int i=tid; i<PIN*PIN; i+=256){ sM1r[i]=m1r[i]; sM1i[i]=m1i[i]; sPjr[i]=pjr[i]; sPji[i]=pji[i]; }
  for (int i=tid; i<FRQ*FRQ; i+=256){ sFxr[i]=fxr[i]; sFxi[i]=fxi[i]; }
  if (tid < PIN)  { sB[tid]      = m1br[tid]; sB[33+tid]  = m1bi[tid]; }
  if (tid < FRQ)  { sB[66+tid]   = fxbr[tid]; sB[99+tid]  = fxbi[tid]; }
  if (tid < POUT) { sB[132+tid]  = pjbr[tid]; sB[165+tid] = pjbi[tid]; }
  __syncthreads();
  // C[f][i] = sum_o e^{-2pi i f o/64} WPW[o][i]
  for (int idx=tid; idx<FRQ*PER; idx+=256){
    int f = idx/PER, i = idx%PER;
    cf acc = make_float2(0.f,0.f);
    #pragma unroll 8
    for (int o=0;o<EMB;++o){ cf e = e64[(f*o)&63]; float w = sW[o*PER+i]; acc.x += w*e.x; acc.y -= w*e.y; }
    C[idx] = acc;
  }
  // d[f] = rfft(WP_b)
  for (int f=tid; f<FRQ; f+=256){
    cf acc = make_float2(0.f,0.f);
    #pragma unroll 8
    for (int o=0;o<EMB;++o){ cf e = e64[(f*o)&63]; acc.x += sWb[o]*e.x; acc.y -= sWb[o]*e.y; }
    s_d[f]=acc;
  }
  // PM = PJ*(I+M1)
  for (int idx=tid; idx<POUT*PIN; idx+=256){
    int q = idx/PIN, pp = idx%PIN;
    cf acc = make_float2(sPjr[q*PIN+pp], sPji[q*PIN+pp]);
    #pragma unroll 6
    for (int p=0;p<PIN;++p){
      cf a = make_float2(sPjr[q*PIN+p], sPji[q*PIN+p]);
      cf b = make_float2(sM1r[p*PIN+pp], sM1i[p*PIN+pp]);
      acc = cmac(acc, a, b);
    }
    PM[idx]=acc;
  }
  // M2 = I + fmix
  for (int idx=tid; idx<FRQ*FRQ; idx+=256){
    int f = idx/FRQ, ff = idx%FRQ;
    cf v = make_float2(sFxr[idx], sFxi[idx]); if (f==ff) v.x += 1.f;
    M2[idx]=v;
  }
  // rowsums of (I+M1)
  for (int p=tid; p<PIN; p+=256){
    cf acc = make_float2(1.f,0.f);
    #pragma unroll 6
    for (int pp=0;pp<PIN;++pp){ acc.x += sM1r[p*PIN+pp]; acc.y += sM1i[p*PIN+pp]; }
    s_rs[p]=acc;
  }
  __syncthreads();
  // o1b[f][p] = d[f]*rs[p] + bm1[p]
  for (int idx=tid; idx<FRQ*PIN; idx+=256){
    int f = idx/PIN, p = idx%PIN;
    cf v = make_float2(0.f,0.f); v = cmac(v, s_d[f], s_rs[p]);
    v.x += sB[p]; v.y += sB[33+p];
    s_o1[idx]=v;
  }
  __syncthreads();
  // o2b[f'][p] = sum_f M2[f',f] o1b[f][p] + bfx[f']
  for (int idx=tid; idx<FRQ*PIN; idx+=256){
    int f = idx/PIN, p = idx%PIN;
    cf acc = make_float2(sB[66+f], sB[99+f]);
    #pragma unroll 4
    for (int ff=0; ff<FRQ; ++ff){
      cf m2 = make_float2(sFxr[f*FRQ+ff], sFxi[f*FRQ+ff]); if (f==ff) m2.x += 1.f;
      acc = cmac(acc, m2, s_o1[ff*PIN+p]);
    }
    s_o2[idx]=acc;
  }
  __syncthreads();
  // o3b[f][q] = sum_p proj[q][p] o2b[f][p] + bp[q]
  for (int idx=tid; idx<FRQ*POUT; idx+=256){
    int f = idx/POUT, q = idx%POUT;
    cf acc = make_float2(sB[132+q], sB[165+q]);
    #pragma unroll 6
    for (int p=0;p<PIN;++p){
      cf a = make_float2(sPjr[q*PIN+p], sPji[q*PIN+p]);
      acc = cmac(acc, a, s_o2[f*PIN+p]);
    }
    o3b[f*POUT+q]=acc;
  }
}

// ---------------- P5: A1 split real/imag planes ----------------
__global__ void p5_a1(const float* __restrict__ fqr, const float* __restrict__ fqi,
                      float* __restrict__ A1r, float* __restrict__ A1i){
  __shared__ cf tbl[720];
  __shared__ cf wrow[DOM];
  int tid=threadIdx.x; int k=blockIdx.x;
  for (int m=tid;m<720;m+=256){ float s,c; sincosf(-2.f*PI_F*(float)m/720.f,&s,&c); tbl[m]=make_float2(c,s); }
  for (int j=tid;j<DOM;j+=256) wrow[j]=make_float2(fqr[k*DOM+j], fqi[k*DOM+j]);
  __syncthreads();
  for (int tau=tid; tau<720; tau+=256){
    cf acc=make_float2(0.f,0.f);
    for (int j=0;j<DOM;++j) acc = cmac(acc, wrow[j], tbl[(j*tau)%720]);
    A1r[k*720+tau]=acc.x;
    A1i[k*720+tau]=acc.y;
  }
}

// ---------------- P5M: Mlow[t][tau] = sum_k Gr[t,k]A1r[k,tau] - Gi[t,k]A1i[k,tau]
__global__ __launch_bounds__(256) void p5m_mlow(const float* __restrict__ A1r,
                                                const float* __restrict__ A1i,
                                                float* __restrict__ Mlow){
  __shared__ float sG[16*144];
  __shared__ float sA[144*16];
  int t0 = blockIdx.y*16, tau0 = blockIdx.x*16;
  int tid = threadIdx.x;
  for (int i=tid; i<16*72; i+=256){
    int tt=i/72, k=i%72;
    int m = ((t0+tt)*k) % 720;
    float s,c; sincosf(2.f*PI_F*(float)m/720.f,&s,&c);
    float sc = (k==0)?(1.f/720.f):(2.f/720.f);
    sG[tt*144+k]    = c*sc;
    sG[tt*144+72+k] = s*sc;
  }
  for (int i=tid; i<72*16; i+=256){
    int k=i/16, tc=i%16;
    sA[k*16+tc]      = A1r[k*720+tau0+tc];
    sA[(72+k)*16+tc] = A1i[k*720+tau0+tc];
  }
  __syncthreads();
  int tt=tid/16, tc=tid%16;
  float acc=0.f;
  #pragma unroll 8
  for (int k=0;k<72;++k)
    acc += sG[tt*144+k]*sA[k*16+tc] - sG[tt*144+72+k]*sA[(72+k)*16+tc];
  Mlow[(size_t)(t0+tt)*720 + tau0+tc] = acc;
}

// ---------------- P_BIG: per-t merged p2+p3+p4+p7 -> V[t], bias[t] ----------------
__global__ __launch_bounds__(256) void p_big(const float* __restrict__ hW,
                    const cf* __restrict__ PM, const cf* __restrict__ M2, const cf* __restrict__ o3b,
                    const float* __restrict__ fbr, const float* __restrict__ fbi,
                    const float* __restrict__ headb,
                    cf* __restrict__ V, float* __restrict__ bias){
  __shared__ cf e64[64];
  __shared__ float shw[1920];
  __shared__ cf sHc[990];
  __shared__ cf sV1[990];
  __shared__ cf sPM[POUT*PIN];
  __shared__ cf sM2[FRQ*FRQ];
  __shared__ cf sO3[FRQ*POUT];
  __shared__ float red[256];
  int tid=threadIdx.x; int t=blockIdx.x;
  if (tid<64){ float s,c; sincosf(2.f*PI_F*tid/64.f,&s,&c); e64[tid]=make_float2(c,s); }
  for (int i=tid;i<1920;i+=256) shw[i]=hW[(size_t)t*1920+i];
  for (int i=tid;i<POUT*PIN;i+=256) sPM[i]=PM[i];
  for (int i=tid;i<FRQ*FRQ;i+=256) sM2[i]=M2[i];
  for (int i=tid;i<FRQ*POUT;i+=256) sO3[i]=o3b[i];
  __syncthreads();
  for (int idx=tid; idx<990; idx+=256){
    int q=idx/FRQ, f=idx%FRQ;
    cf acc=make_float2(0.f,0.f);
    const float* hw = &shw[q*64];
    for (int o=0;o<EMB;++o){ cf e=e64[(f*o)&63]; float w=hw[o]; acc.x+=w*e.x; acc.y+=w*e.y; }
    float s=((f==0)||(f==32))?(1.f/64.f):(2.f/64.f);
    sHc[idx]=make_float2(acc.x*s, acc.y*s);
  }
  __syncthreads();
  for (int idx=tid; idx<990; idx+=256){
    int f=idx/PIN, p=idx%PIN;
    cf acc=make_float2(0.f,0.f);
    for (int q=0;q<POUT;++q) acc=cmac(acc, sHc[q*FRQ+f], sPM[q*PIN+p]);
    sV1[idx]=acc;
  }
  __syncthreads();
  for (int idx=tid; idx<990; idx+=256){
    int ff=idx/PIN, pp=idx%PIN;
    cf acc=make_float2(0.f,0.f);
    for (int f=0;f<FRQ;++f) acc=cmac(acc, sV1[f*PIN+pp], sM2[f*FRQ+ff]);
    V[(size_t)t*990+idx]=acc;
  }
  float part=0.f;
  for (int idx=tid; idx<990; idx+=256){
    int q=idx/FRQ, f=idx%FRQ;
    cf h=sHc[idx]; cf o=sO3[f*POUT+q];
    part += h.x*o.x - h.y*o.y;
  }
  part *= 0.7f;
  if (tid<DOM){
    int m=(tid*t)%720; float s,c; sincosf(2.f*PI_F*(float)m/720.f,&s,&c);
    float sc=(tid==0)?(1.f/720.f):(2.f/720.f);
    part += 0.3f*sc*(c*fbr[tid] - s*fbi[tid]);
  }
  red[tid]=part; __syncthreads();
  for (int s=128;s>0;s>>=1){ if (tid<s) red[tid]+=red[tid+s]; __syncthreads(); }
  if (tid==0) bias[t] = red[0] + 0.7f*headb[t];
}

// ---------------- P6: build fused bf16 weight row t ----------------
__global__ void p6_bt(const cf* __restrict__ V, const cf* __restrict__ C,
                      const float* __restrict__ Mlow, __hip_bfloat16* __restrict__ BTm){
  __shared__ cf sV[990];
  __shared__ cf sC[FRQ*PER];
  int tid=threadIdx.x; int t=blockIdx.x;
  for (int i=tid;i<990;i+=256) sV[i]=V[(size_t)t*990+i];
  for (int i=tid;i<FRQ*PER;i+=256) sC[i]=C[i];
  __syncthreads();
  const float* ml = Mlow + (size_t)t*720;
  for (int tau=tid; tau<720; tau+=256){
    int p0 = tau/PER, i0 = tau - p0*PER;
    float mper=0.f;
    for (int f=0; f<FRQ; ++f){ cf v=sV[f*PIN+p0]; cf c=sC[f*PER+i0]; mper += v.x*c.x - v.y*c.y; }
    BTm[(size_t)t*KP + tau] = __float2bfloat16(0.3f*ml[tau] + 0.7f*mper);
  }
  for (int j=tid;j<KP-SEQ;j+=256){
    float v = 0.f;
    if (j < KW){ int p=j/FRQ, f=j-p*FRQ; v = 0.7f * sV[f*PIN+p].x; }
    BTm[(size_t)t*KP + SEQ + j] = __float2bfloat16(v);
  }
}

// ---------------- R1: x[b][t][n] -> Abig[b*128+n][t] (bf16, 64x64 tiles, short4 stores)
__global__ __launch_bounds__(256) void r1_x(const float* __restrict__ x, __hip_bfloat16* __restrict__ Abig){
  __shared__ float tile[64][65];
  int b = blockIdx.z; int t0=blockIdx.y*64; int n0=blockIdx.x*64;
  int tid=threadIdx.x;
  int c = tid & 63, r0 = tid >> 6;
  #pragma unroll
  for (int s=0;s<16;++s){
    int r = r0 + s*4;
    int t = t0 + r;
    tile[r][c] = (t<SEQ) ? x[((size_t)b*SEQ + t)*NCH + n0 + c] : 0.f;
  }
  __syncthreads();
  int nn0 = tid >> 4;
  int tq  = tid & 15;
  int tt  = t0 + tq*4;
  #pragma unroll
  for (int s=0;s<4;++s){
    int nn = nn0 + s*16;
    short4 v;
    v.x = b2s(tile[tq*4+0][nn]);
    v.y = b2s(tile[tq*4+1][nn]);
    v.z = b2s(tile[tq*4+2][nn]);
    v.w = b2s(tile[tq*4+3][nn]);
    __hip_bfloat16* dst = Abig + (size_t)(b*NCH + n0+nn)*KP + tt;
    if (tt+3 < SEQ){
      *reinterpret_cast<short4*>(dst) = v;
    } else {
      short sv[4] = {v.x, v.y, v.z, v.w};
      for (int j=0;j<4;++j) if (tt+j < SEQ) *reinterpret_cast<short*>(dst+j) = sv[j];
    }
  }
}

// ---------------- R2: Wpos rows -> Abig cols [720,1728), vectorized
__global__ __launch_bounds__(256) void r2_wpos(const float* __restrict__ Wp, __hip_bfloat16* __restrict__ Abig){
  int bn = blockIdx.x; int tid=threadIdx.x;
  int j = tid*4;
  if (j >= KP-SEQ) return;
  const float* src = Wp + (size_t)bn*KW;
  float f0,f1,f2,f3;
  if (j+3 < KW){
    float2 u = *reinterpret_cast<const float2*>(src+j);
    float2 w = *reinterpret_cast<const float2*>(src+j+2);
    f0=u.x; f1=u.y; f2=w.x; f3=w.y;
  } else {
    f0=(j  <KW)?src[j  ]:0.f; f1=(j+1<KW)?src[j+1]:0.f;
    f2=(j+2<KW)?src[j+2]:0.f; f3=(j+3<KW)?src[j+3]:0.f;
  }
  short4 v = { b2s(f0), b2s(f1), b2s(f2), b2s(f3) };
  *reinterpret_cast<short4*>(Abig + (size_t)bn*KP + SEQ + j) = v;
}

// ---------------- GEMM: out[b,t,n] = sum_k BT[t,k]*Abig[bn,k] + bias[t] (f32 out)
typedef __attribute__((ext_vector_type(8))) short bfrag_t;
typedef __attribute__((ext_vector_type(4))) float accf_t;
typedef __attribute__((address_space(1))) void gvoid;
typedef __attribute__((address_space(3))) void lvoid;

__device__ __forceinline__ void gload16(const void* g, void* l){
  __builtin_amdgcn_global_load_lds((gvoid*)(g), (lvoid*)(l), 16, 0, 0);
}

__global__ __launch_bounds__(256) void gemm_main(const __hip_bfloat16* __restrict__ BTm,
                                                 const __hip_bfloat16* __restrict__ Abig,
                                                 const float* __restrict__ bias,
                                                 float* __restrict__ out)
{
  __shared__ __hip_bfloat16 At[128*32];
  __shared__ __hip_bfloat16 Bt[128*32];
  int tid = threadIdx.x;
  int lane = tid & 63;
  int wv = tid >> 6;
  int wr = wv >> 1, wc = wv & 1;
  int t0 = blockIdx.y*128, bn0 = blockIdx.x*128;

  accf_t acc[4][4];
  #pragma unroll
  for (int i=0;i<4;++i)
    #pragma unroll
    for (int j=0;j<4;++j) acc[i][j] = (accf_t){0.f,0.f,0.f,0.f};

  int lin0 = tid, lin1 = 256+tid;
  int row0 = lin0>>2, ug0 = (lin0&3) ^ ((row0>>1)&3);
  int row1 = lin1>>2, ug1 = (lin1&3) ^ ((row1>>1)&3);
  const __hip_bfloat16* gA0 = BTm  + (size_t)(t0 +row0)*KP + ug0*8;
  const __hip_bfloat16* gA1 = BTm  + (size_t)(t0 +row1)*KP + ug1*8;
  const __hip_bfloat16* gB0 = Abig + (size_t)(bn0+row0)*KP + ug0*8;
  const __hip_bfloat16* gB1 = Abig + (size_t)(bn0+row1)*KP + ug1*8;
  char* lA0 = (char*)At + lin0*16; char* lA1 = (char*)At + lin1*16;
  char* lB0 = (char*)Bt + lin0*16; char* lB1 = (char*)Bt + lin1*16;

  int g = lane>>4;
  int arow = wr*64 + (lane&15);
  int brow = wc*64 + (lane&15);

  for (int ks=0; ks<KP/32; ++ks){
    int k0 = ks*32;
    gload16(gA0 + k0, lA0);
    gload16(gA1 + k0, lA1);
    gload16(gB0 + k0, lB0);
    gload16(gB1 + k0, lB1);
    __syncthreads();
    bfrag_t af[4], bb[4];
    #pragma unroll
    for (int mi=0;mi<4;++mi){
      int r = arow + mi*16;
      int uu = g ^ ((r>>1)&3);
      af[mi] = *(const bfrag_t*)((const char*)At + r*64 + uu*16);
    }
    #pragma unroll
    for (int ni=0;ni<4;++ni){
      int r = brow + ni*16;
      int uu = g ^ ((r>>1)&3);
      bb[ni] = *(const bfrag_t*)((const char*)Bt + r*64 + uu*16);
    }
    #pragma unroll
    for (int mi=0;mi<4;++mi)
      #pragma unroll
      for (int ni=0;ni<4;++ni)
        acc[mi][ni] = __builtin_amdgcn_mfma_f32_16x16x32_bf16(af[mi], bb[ni], acc[mi][ni], 0, 0, 0);
    __syncthreads();
  }

  #pragma unroll
  for (int mi=0;mi<4;++mi){
    int tbase = t0 + wr*64 + mi*16 + (lane>>4)*4;
    #pragma unroll
    for (int ni=0;ni<4;++ni){
      int col = bn0 + wc*64 + ni*16 + (lane&15);
      int b = col>>7, n = col&127;
      size_t obase = (size_t)b*(SEQ*NCH) + n;
      #pragma unroll
      for (int r=0;r<4;++r){
        int t = tbase + r;
        if (t<SEQ) out[obase + (size_t)t*NCH] = acc[mi][ni][r] + bias[t];
      }
    }
  }
}

extern "C" void kernel_launch(void* const* d_in, const int* in_sizes, int n_in,
                              void* d_out, int out_size, void* d_ws, size_t ws_size,
                              hipStream_t stream)
{
  const float* x     = (const float*)d_in[0];
  const float* fqWr  = (const float*)d_in[1];
  const float* fqWi  = (const float*)d_in[2];
  const float* fqbr  = (const float*)d_in[3];
  const float* fqbi  = (const float*)d_in[4];
  const float* WPW   = (const float*)d_in[5];
  const float* WPb   = (const float*)d_in[6];
  const float* Wpos  = (const float*)d_in[7];
  const float* m1r   = (const float*)d_in[8];
  const float* m1i   = (const float*)d_in[9];
  const float* m1br  = (const float*)d_in[10];
  const float* m1bi  = (const float*)d_in[11];
  const float* fxr   = (const float*)d_in[12];
  const float* fxi   = (const float*)d_in[13];
  const float* fxbr  = (const float*)d_in[14];
  const float* fxbi  = (const float*)d_in[15];
  const float* pjr   = (const float*)d_in[16];
  const float* pji   = (const float*)d_in[17];
  const float* pjbr  = (const float*)d_in[18];
  const float* pjbi  = (const float*)d_in[19];
  const float* headW = (const float*)d_in[20];
  const float* headb = (const float*)d_in[21];

  char* ws = (char*)d_ws;
  size_t off = 0;
  auto alloc = [&](size_t bytes)->void*{ void* p = ws + off; off += (bytes + 255) & ~(size_t)255; return p; };
  __hip_bfloat16* Abig = (__hip_bfloat16*)alloc((size_t)BN*KP*2);
  __hip_bfloat16* BTm  = (__hip_bfloat16*)alloc((size_t)MT*KP*2);
  cf* V    = (cf*)alloc((size_t)SEQ*990*8);
  float* A1r = (float*)alloc((size_t)DOM*720*4);
  float* A1i = (float*)alloc((size_t)DOM*720*4);
  float* Mlow= (float*)alloc((size_t)SEQ*720*4);
  cf* C   = (cf*)alloc((size_t)FRQ*PER*8);
  cf* PM  = (cf*)alloc((size_t)POUT*PIN*8);
  cf* M2  = (cf*)alloc((size_t)FRQ*FRQ*8);
  cf* o3b = (cf*)alloc((size_t)FRQ*POUT*8);
  float* bias = (float*)alloc((size_t)SEQ*4);

  p1_small<<<1,256,0,stream>>>(WPW,WPb, m1r,m1i,m1br,m1bi, fxr,fxi,fxbr,fxbi, pjr,pji,pjbr,pjbi,
                               C,PM,M2,o3b);
  p5_a1<<<DOM,256,0,stream>>>(fqWr, fqWi, A1r, A1i);
  p5m_mlow<<<dim3(45,45),256,0,stream>>>(A1r, A1i, Mlow);
  p_big<<<SEQ,256,0,stream>>>(headW, PM, M2, o3b, fqbr, fqbi, headb, V, bias);
  p6_bt<<<SEQ,256,0,stream>>>(V, C, Mlow, BTm);
  r1_x<<<dim3(2,12,BATCH), 256, 0, stream>>>(x, Abig);
  r2_wpos<<<BN,256,0,stream>>>(Wpos, Abig);
  gemm_main<<<dim3(BN/128, MT/128), 256, 0, stream>>>(BTm, Abig, bias, (float*)d_out);
}